// Round 11
// baseline (176.695 us; speedup 1.0000x reference)
//
#include <hip/hip_runtime.h>
#include <hip/hip_fp16.h>

// LJ reduced units: sigma=1, eps=1, cutoff=2.5
// e_pair = 4*(sr6^2 - sr6) - SHIFT, SHIFT = -0.0163168896
// half  = 0.5*e_pair = 2*(sr6^2 - sr6) + 0.0081584448
__device__ __forceinline__ float half_lj(float r2) {
    float sr2 = 1.0f / r2;
    float sr6 = sr2 * sr2 * sr2;
    return fmaf(2.0f, sr6 * sr6 - sr6, 0.0081584448f);
}

// ---------- Path A: 16-slice ballot bin + block-wide barrier-claim accum ----
// slice = atom >> 14 (16 slices of 16384 atoms; needs n_atoms <= 262144)
#define SL_SHIFT 14
#define SL_SZ    16384
#define NSL      16
#define CAP1     176      // per-(wave,slice) staging cap (mean 128, +4.4 sigma)
#define QPB      1024     // quad-pairs per bin block -> 8192 records
#define GC_STRIDE 32      // gcnt padding: 128 B per counter

__device__ __forceinline__ unsigned pack_rec(int atom, float e) {
    unsigned h = (unsigned)__half_as_ushort(__float2half(e));
    return (h << 16) | ((unsigned)atom & (SL_SZ - 1));
}

// K1: fused energy + 16-way ballot-rank binning (r9-proven core).
// ZERO LDS atomics: 4 ballots group lanes by slice; group leader bumps a
// wave-private cursor with a plain LDS RMW. Dump to monolithic slice-major
// grec[s][cap] via one padded global reservation atomic per (block,slice).
__global__ __launch_bounds__(256)
void bin_kernel(const int4* __restrict__ pairs4, const float4* __restrict__ dist4,
                unsigned* __restrict__ grec, unsigned* __restrict__ gcnt,
                float* __restrict__ ovf, int npair4, int cap) {
    __shared__ unsigned staged[4][NSL][CAP1];     // 44 KB
    __shared__ unsigned short cnt1[4][NSL];
    __shared__ unsigned short dbase[4][NSL];
    __shared__ unsigned gbase[NSL];
    const int tid = threadIdx.x;
    const int wave = tid >> 6, lane = tid & 63;
    const unsigned long long ltmask = (1ULL << lane) - 1ULL;
    if (tid < 64) cnt1[tid >> 4][tid & 15] = 0;
    __syncthreads();

    for (int k = 0; k < 4; ++k) {
        int q = blockIdx.x * QPB + (k << 8) + tid;
        bool valid = q < npair4;
        unsigned recs[8]; int ss[8];
        if (valid) {
            int4 pA = pairs4[2 * q];
            int4 pB = pairs4[2 * q + 1];
            float4 d0 = dist4[3 * q], d1 = dist4[3 * q + 1], d2 = dist4[3 * q + 2];
            float e0 = half_lj(fmaf(d0.x, d0.x, fmaf(d0.y, d0.y, d0.z * d0.z)));
            float e1 = half_lj(fmaf(d0.w, d0.w, fmaf(d1.x, d1.x, d1.y * d1.y)));
            float e2 = half_lj(fmaf(d1.z, d1.z, fmaf(d1.w, d1.w, d2.x * d2.x)));
            float e3 = half_lj(fmaf(d2.y, d2.y, fmaf(d2.z, d2.z, d2.w * d2.w)));
            recs[0] = pack_rec(pA.x, e0); ss[0] = (unsigned)pA.x >> SL_SHIFT;
            recs[1] = pack_rec(pA.y, e0); ss[1] = (unsigned)pA.y >> SL_SHIFT;
            recs[2] = pack_rec(pA.z, e1); ss[2] = (unsigned)pA.z >> SL_SHIFT;
            recs[3] = pack_rec(pA.w, e1); ss[3] = (unsigned)pA.w >> SL_SHIFT;
            recs[4] = pack_rec(pB.x, e2); ss[4] = (unsigned)pB.x >> SL_SHIFT;
            recs[5] = pack_rec(pB.y, e2); ss[5] = (unsigned)pB.y >> SL_SHIFT;
            recs[6] = pack_rec(pB.z, e3); ss[6] = (unsigned)pB.z >> SL_SHIFT;
            recs[7] = pack_rec(pB.w, e3); ss[7] = (unsigned)pB.w >> SL_SHIFT;
        }
        unsigned long long vmask = __ballot(valid);
#pragma unroll
        for (int r = 0; r < 8; ++r) {
            int s = valid ? ss[r] : 0;
            unsigned long long b0 = __ballot(s & 1);
            unsigned long long b1 = __ballot(s & 2);
            unsigned long long b2 = __ballot(s & 4);
            unsigned long long b3 = __ballot(s & 8);
            unsigned long long m = ((s & 1) ? b0 : ~b0) & ((s & 2) ? b1 : ~b1) &
                                   ((s & 4) ? b2 : ~b2) & ((s & 8) ? b3 : ~b3) & vmask;
            int leader = __ffsll((unsigned long long)m) - 1;
            if (leader < 0) leader = 0;
            int rank = (int)__popcll(m & ltmask);
            int gcount = (int)__popcll(m);
            int pos0 = 0;
            if (valid && lane == leader) {        // plain RMW: distinct cells
                pos0 = (int)cnt1[wave][s];
                cnt1[wave][s] = (unsigned short)(pos0 + gcount);
            }
            pos0 = __shfl(pos0, leader, 64);
            if (valid) {
                int pos = pos0 + rank;
                if (pos < CAP1) {
                    staged[wave][s][pos] = recs[r];
                } else {   // ~4.4-sigma tail: accumulate via overflow replica
                    int atom = (s << SL_SHIFT) | (int)(recs[r] & (SL_SZ - 1));
                    float e = __half2float(__ushort_as_half((unsigned short)(recs[r] >> 16)));
                    unsafeAtomicAdd(&ovf[atom], e);
                }
            }
        }
    }
    __syncthreads();

    // one padded reservation atomic per (block,slice); per-wave sub-bases
    if (tid < NSL) {
        int s = tid;
        int c0 = min((int)cnt1[0][s], CAP1);
        int c1 = min((int)cnt1[1][s], CAP1);
        int c2 = min((int)cnt1[2][s], CAP1);
        int c3 = min((int)cnt1[3][s], CAP1);
        gbase[s] = atomicAdd(&gcnt[s * GC_STRIDE], (unsigned)(c0 + c1 + c2 + c3));
        dbase[0][s] = 0;
        dbase[1][s] = (unsigned short)c0;
        dbase[2][s] = (unsigned short)(c0 + c1);
        dbase[3][s] = (unsigned short)(c0 + c1 + c2);
    }
    __syncthreads();

    // slot-parallel dump: 4*16*CAP1 slots, i fastest (long coalesced runs)
    const int nslots = 4 * NSL * CAP1;
    for (int idx = tid; idx < nslots; idx += 256) {
        int w = idx / (NSL * CAP1);
        int rem = idx - w * (NSL * CAP1);
        int s = rem / CAP1;
        int i = rem - s * CAP1;
        if (i < min((int)cnt1[w][s], CAP1)) {
            unsigned pos = gbase[s] + dbase[w][s] + (unsigned)i;
            if (pos < (unsigned)cap)
                grec[(size_t)s * cap + pos] = staged[w][s][i];
        }
    }
}

// K1 tail: leftover pairs (npairs % 4) -> overflow replica.
__global__ void bin_tail_kernel(const int* __restrict__ pairs,
                                const float* __restrict__ dist,
                                float* __restrict__ ovf,
                                int start, int npairs) {
    int i = start + blockIdx.x * 64 + threadIdx.x;
    if (i >= npairs) return;
    float dx = dist[3 * i], dy = dist[3 * i + 1], dz = dist[3 * i + 2];
    float h = half_lj(fmaf(dx, dx, fmaf(dy, dy, dz * dz)));
    unsafeAtomicAdd(&ovf[pairs[2 * i]], h);
    unsafeAtomicAdd(&ovf[pairs[2 * i + 1]], h);
}

// K2: block-wide barrier-claim accumulate. ZERO atomics, ZERO redundancy.
// Block (s,c) owns all 16384 atoms of slice s (acc 64KB + 16-bit tag 32KB)
// and reads its contiguous chunk of slice s's record list. Per round, all
// active (thread,record) claims write tag[a]=tid; after a barrier, winners
// do a plain acc RMW (distinct addresses block-wide). Same-thread duplicate
// addresses retire together (sequential RMWs by one thread are safe).
__global__ __launch_bounds__(1024)
void accum_bt_kernel(const unsigned* __restrict__ grec,
                     const unsigned* __restrict__ gcnt,
                     float* __restrict__ rep,
                     int cap, int CH, int n_pad) {
    __shared__ float acc[SL_SZ];              // 64 KB
    __shared__ unsigned short tag[SL_SZ];     // 32 KB (no init needed)
    const int s = blockIdx.x / CH;
    const int c = blockIdx.x % CH;
    const int tid = threadIdx.x;

    float4* acc4 = (float4*)acc;
    for (int i = tid; i < SL_SZ / 4; i += 1024)
        acc4[i] = make_float4(0.f, 0.f, 0.f, 0.f);
    __syncthreads();

    int M = (int)gcnt[s * GC_STRIDE];
    if (M > cap) M = cap;
    const unsigned* base = grec + (size_t)s * cap;
    const int beg = (int)((long long)c * M / CH);
    const int end = (int)((long long)(c + 1) * M / CH);

    for (int jj = beg; jj < end; jj += 4096) {
        int a[4]; float v[4];
        unsigned actm = 0;
#pragma unroll
        for (int r = 0; r < 4; ++r) {
            int j = jj + (r << 10) + tid;
            if (j < end) {
                unsigned rec = base[j];
                a[r] = (int)(rec & (SL_SZ - 1));
                v[r] = __half2float(__ushort_as_half((unsigned short)(rec >> 16)));
                actm |= 1u << r;
            }
        }
        while (__syncthreads_or((int)actm)) {
#pragma unroll
            for (int r = 0; r < 4; ++r)
                if (actm & (1u << r)) tag[a[r]] = (unsigned short)tid;
            __syncthreads();
#pragma unroll
            for (int r = 0; r < 4; ++r)
                if ((actm & (1u << r)) && tag[a[r]] == (unsigned short)tid) {
                    acc[a[r]] += v[r];
                    actm &= ~(1u << r);
                }
        }
    }
    __syncthreads();

    float4* rep4 = (float4*)(rep + (size_t)c * n_pad + (size_t)s * SL_SZ);
    for (int i = tid; i < SL_SZ / 4; i += 1024)
        rep4[i] = acc4[i];
}

// K3: out = sum over B replicas (last one is the overflow replica).
__global__ void reduce_reps_kernel(const float* __restrict__ rep,
                                   float* __restrict__ out,
                                   int n_atoms, int n_pad, int B) {
    int i4 = blockIdx.x * blockDim.x + threadIdx.x;
    int n4 = n_atoms / 4;
    if (i4 < n4) {
        float4 sum = make_float4(0.f, 0.f, 0.f, 0.f);
        for (int b = 0; b < B; ++b) {
            float4 v = *(const float4*)(rep + (size_t)b * n_pad + 4 * (size_t)i4);
            sum.x += v.x; sum.y += v.y; sum.z += v.z; sum.w += v.w;
        }
        ((float4*)out)[i4] = sum;
    }
    if (i4 == 0) {
        for (int i = n4 * 4; i < n_atoms; ++i) {
            float sum = 0.f;
            for (int b = 0; b < B; ++b) sum += rep[(size_t)b * n_pad + i];
            out[i] = sum;
        }
    }
}

// ---------- Path B fallback: slice-scan (measured 125 us) ----------
#define PB_SHIFT 15
#define PB_SZ 32768

__global__ void compute_e8_kernel(const float4* __restrict__ dist4,
                                  uint4* __restrict__ e8, int npair8) {
    int t = blockIdx.x * blockDim.x + threadIdx.x;
    if (t >= npair8) return;
    float4 v0 = dist4[6 * t + 0], v1 = dist4[6 * t + 1], v2 = dist4[6 * t + 2];
    float4 v3 = dist4[6 * t + 3], v4 = dist4[6 * t + 4], v5 = dist4[6 * t + 5];
    float h0 = half_lj(fmaf(v0.x, v0.x, fmaf(v0.y, v0.y, v0.z * v0.z)));
    float h1 = half_lj(fmaf(v0.w, v0.w, fmaf(v1.x, v1.x, v1.y * v1.y)));
    float h2 = half_lj(fmaf(v1.z, v1.z, fmaf(v1.w, v1.w, v2.x * v2.x)));
    float h3 = half_lj(fmaf(v2.y, v2.y, fmaf(v2.z, v2.z, v2.w * v2.w)));
    float h4 = half_lj(fmaf(v3.x, v3.x, fmaf(v3.y, v3.y, v3.z * v3.z)));
    float h5 = half_lj(fmaf(v3.w, v3.w, fmaf(v4.x, v4.x, v4.y * v4.y)));
    float h6 = half_lj(fmaf(v4.z, v4.z, fmaf(v4.w, v4.w, v5.x * v5.x)));
    float h7 = half_lj(fmaf(v5.y, v5.y, fmaf(v5.z, v5.z, v5.w * v5.w)));
    union { __half2 h; unsigned u; } c01, c23, c45, c67;
    c01.h = __floats2half2_rn(h0, h1);
    c23.h = __floats2half2_rn(h2, h3);
    c45.h = __floats2half2_rn(h4, h5);
    c67.h = __floats2half2_rn(h6, h7);
    uint4 o; o.x = c01.u; o.y = c23.u; o.z = c45.u; o.w = c67.u;
    e8[t] = o;
}

__global__ void compute_e_tail_kernel(const float* __restrict__ dist,
                                      __half* __restrict__ eh,
                                      int start, int npairs) {
    int i = start + blockIdx.x * blockDim.x + threadIdx.x;
    if (i >= npairs) return;
    float dx = dist[3 * i], dy = dist[3 * i + 1], dz = dist[3 * i + 2];
    eh[i] = __float2half(half_lj(fmaf(dx, dx, fmaf(dy, dy, dz * dz))));
}

__global__ __launch_bounds__(1024, 1)
void accum_slice_kernel(const int4* __restrict__ pairs4,
                        const uint2* __restrict__ eh2,
                        const int* __restrict__ pairs,
                        const __half* __restrict__ eh,
                        float* __restrict__ rep,
                        int npair4, int npairs, int nslices, int B, int n_pad) {
    __shared__ float lds[PB_SZ];
    int gid = blockIdx.x;
    int s = gid % nslices;
    int b = gid / nslices;
    const int tid = threadIdx.x;
    const int base = s << PB_SHIFT;

    float4* lds4 = (float4*)lds;
    for (int i = tid; i < PB_SZ / 4; i += 1024)
        lds4[i] = make_float4(0.f, 0.f, 0.f, 0.f);
    __syncthreads();

    const int qb = (int)((long long)b * npair4 / B);
    const int qe = (int)((long long)(b + 1) * npair4 / B);

#define CHK(atom, val)                                           \
    do {                                                         \
        int _t = (atom) - base;                                  \
        if ((unsigned)_t < PB_SZ) atomicAdd(&lds[_t], (val));    \
    } while (0)

    for (int q = qb + tid; q < qe; q += 1024) {
        int4 pA = pairs4[2 * q];
        int4 pB = pairs4[2 * q + 1];
        uint2 ue = eh2[q];
        union { unsigned u; __half2 h; } a_, b_;
        a_.u = ue.x; b_.u = ue.y;
        float2 e01 = __half22float2(a_.h);
        float2 e23 = __half22float2(b_.h);
        CHK(pA.x, e01.x); CHK(pA.y, e01.x);
        CHK(pA.z, e01.y); CHK(pA.w, e01.y);
        CHK(pB.x, e23.x); CHK(pB.y, e23.x);
        CHK(pB.z, e23.y); CHK(pB.w, e23.y);
    }
    if (b == 0) {
        for (int i = npair4 * 4 + tid; i < npairs; i += 1024) {
            int a0 = pairs[2 * i], a1 = pairs[2 * i + 1];
            float h = __half2float(eh[i]);
            CHK(a0, h);
            CHK(a1, h);
        }
    }
#undef CHK
    __syncthreads();

    float4* rep4 = (float4*)(rep + (size_t)b * n_pad + (size_t)s * PB_SZ);
    for (int i = tid; i < PB_SZ / 4; i += 1024)
        rep4[i] = lds4[i];
}

// ---------- Path C fallback: direct agent atomics (measured 803 us) ----------
__global__ void lj_vec4_agent_kernel(const int4* __restrict__ pairs4,
                                     const float4* __restrict__ dist4,
                                     float* __restrict__ out, int npair4) {
    int t = blockIdx.x * blockDim.x + threadIdx.x;
    if (t >= npair4) return;
    int4 p01 = pairs4[2 * t];
    int4 p23 = pairs4[2 * t + 1];
    float4 d0 = dist4[3 * t];
    float4 d1 = dist4[3 * t + 1];
    float4 d2 = dist4[3 * t + 2];
    float h0 = half_lj(fmaf(d0.x, d0.x, fmaf(d0.y, d0.y, d0.z * d0.z)));
    float h1 = half_lj(fmaf(d0.w, d0.w, fmaf(d1.x, d1.x, d1.y * d1.y)));
    float h2 = half_lj(fmaf(d1.z, d1.z, fmaf(d1.w, d1.w, d2.x * d2.x)));
    float h3 = half_lj(fmaf(d2.y, d2.y, fmaf(d2.z, d2.z, d2.w * d2.w)));
    unsafeAtomicAdd(&out[p01.x], h0);
    unsafeAtomicAdd(&out[p01.y], h0);
    unsafeAtomicAdd(&out[p01.z], h1);
    unsafeAtomicAdd(&out[p01.w], h1);
    unsafeAtomicAdd(&out[p23.x], h2);
    unsafeAtomicAdd(&out[p23.y], h2);
    unsafeAtomicAdd(&out[p23.z], h3);
    unsafeAtomicAdd(&out[p23.w], h3);
}

__global__ void lj_tail_agent_kernel(const int* __restrict__ pairs,
                                     const float* __restrict__ dist,
                                     float* __restrict__ out,
                                     int start, int npairs) {
    int i = start + blockIdx.x * blockDim.x + threadIdx.x;
    if (i >= npairs) return;
    float dx = dist[3 * i], dy = dist[3 * i + 1], dz = dist[3 * i + 2];
    float h = half_lj(fmaf(dx, dx, fmaf(dy, dy, dz * dz)));
    unsafeAtomicAdd(&out[pairs[2 * i]], h);
    unsafeAtomicAdd(&out[pairs[2 * i + 1]], h);
}

extern "C" void kernel_launch(void* const* d_in, const int* in_sizes, int n_in,
                              void* d_out, int out_size, void* d_ws, size_t ws_size,
                              hipStream_t stream) {
    const int* pairs = (const int*)d_in[0];      // [P, 2] int32
    const float* dist = (const float*)d_in[1];   // [P, 3] float32
    float* out = (float*)d_out;                  // [n_atoms] float32

    const int n_atoms = out_size;
    const int npairs = in_sizes[0] / 2;
    const int npair4 = npairs / 4;

    // ---- Path A: 16-slice ballot bin + barrier-claim accumulate ----
    if (n_atoms <= NSL * SL_SZ && npairs > 0) {
        const int nslices = (n_atoms + SL_SZ - 1) >> SL_SHIFT;
        const int n_pad = nslices << SL_SHIFT;
        // per-slice mean 2P/16 (~1.05M), sigma ~1K; +16384 = 16 sigma
        int cap = (int)(2LL * npairs / NSL + 16384);
        size_t cnt_bytes = (size_t)NSL * GC_STRIDE * 4;   // 2 KB padded counters
        size_t rec_bytes = (size_t)NSL * (size_t)cap * 4;
        int CH = 16;
        while (CH > 4 && cnt_bytes + rec_bytes +
                             (size_t)(CH + 1) * n_pad * 4 > ws_size)
            CH >>= 1;
        size_t need = cnt_bytes + rec_bytes + (size_t)(CH + 1) * n_pad * 4;
        if (need <= ws_size) {
            unsigned* gcnt = (unsigned*)d_ws;
            unsigned* grec = (unsigned*)((char*)d_ws + cnt_bytes);
            float* rep = (float*)((char*)d_ws + cnt_bytes + rec_bytes);
            float* ovf = rep + (size_t)CH * n_pad;   // overflow replica

            hipMemsetAsync(gcnt, 0, cnt_bytes, stream);
            hipMemsetAsync(ovf, 0, (size_t)n_pad * 4, stream);

            int nb = (npair4 + QPB - 1) / QPB;
            if (nb > 0)
                bin_kernel<<<nb, 256, 0, stream>>>(
                    (const int4*)pairs, (const float4*)dist, grec, gcnt, ovf,
                    npair4, cap);
            if (npair4 * 4 < npairs)
                bin_tail_kernel<<<1, 64, 0, stream>>>(pairs, dist, ovf,
                                                      npair4 * 4, npairs);

            accum_bt_kernel<<<nslices * CH, 1024, 0, stream>>>(
                grec, gcnt, rep, cap, CH, n_pad);

            int n4 = n_atoms / 4;
            int grid = (n4 + 255) / 256;
            if (grid == 0) grid = 1;
            reduce_reps_kernel<<<grid, 256, 0, stream>>>(rep, out, n_atoms,
                                                         n_pad, CH + 1);
            return;
        }
    }

    // ---- Path B: slice-scan ----
    {
        const int nsl = (n_atoms + PB_SZ - 1) >> PB_SHIFT;
        const int n_pad = nsl << PB_SHIFT;
        const size_t e_elems = (size_t)((npairs + 7) / 8) * 8;
        const size_t e_bytes = e_elems * sizeof(__half);
        int B = 32;
        while (B > 8 && e_bytes + (size_t)B * n_pad * sizeof(float) > ws_size)
            B >>= 1;
        if (e_bytes + (size_t)B * n_pad * sizeof(float) <= ws_size) {
            __half* eh = (__half*)d_ws;
            float* rep = (float*)((char*)d_ws + e_bytes);
            int npair8 = npairs / 8;
            if (npair8 > 0)
                compute_e8_kernel<<<(npair8 + 255) / 256, 256, 0, stream>>>(
                    (const float4*)dist, (uint4*)eh, npair8);
            if (npair8 * 8 < npairs)
                compute_e_tail_kernel<<<1, 64, 0, stream>>>(dist, eh,
                                                            npair8 * 8, npairs);
            accum_slice_kernel<<<nsl * B, 1024, 0, stream>>>(
                (const int4*)pairs, (const uint2*)eh, pairs, eh, rep,
                npair4, npairs, nsl, B, n_pad);
            int n4 = n_atoms / 4;
            int grid = (n4 + 255) / 256;
            if (grid == 0) grid = 1;
            reduce_reps_kernel<<<grid, 256, 0, stream>>>(rep, out, n_atoms,
                                                         n_pad, B);
            return;
        }
    }

    // ---- Path C: direct atomics ----
    hipMemsetAsync(d_out, 0, (size_t)out_size * sizeof(float), stream);
    if (npair4 > 0)
        lj_vec4_agent_kernel<<<(npair4 + 255) / 256, 256, 0, stream>>>(
            (const int4*)pairs, (const float4*)dist, out, npair4);
    if (npair4 * 4 < npairs)
        lj_tail_agent_kernel<<<1, 64, 0, stream>>>(pairs, dist, out,
                                                   npair4 * 4, npairs);
}

// Round 12
// 130.805 us; speedup vs baseline: 1.3508x; 1.3508x over previous
//
#include <hip/hip_runtime.h>
#include <hip/hip_fp16.h>

// LJ reduced units: sigma=1, eps=1, cutoff=2.5
// e_pair = 4*(sr6^2 - sr6) - SHIFT, SHIFT = -0.0163168896
// half  = 0.5*e_pair = 2*(sr6^2 - sr6) + 0.0081584448
__device__ __forceinline__ float half_lj(float r2) {
    float sr2 = 1.0f / r2;
    float sr6 = sr2 * sr2 * sr2;
    return fmaf(2.0f, sr6 * sr6 - sr6, 0.0081584448f);
}

// ---------- Path A: r7 pipeline, occupancy-tuned ----------
// bucket = atom >> 10 (256 buckets of 1024 atoms; needs n_atoms <= 262144)
// slice  = bucket >> 4 (16 slices of 16384 atoms = 64 KB accumulator)
#define SL_SHIFT 14
#define SL_SZ    16384
#define NB       256
#define BCAP     28       // per-bucket staging cap per bin block (mean 16, +3 sigma)
#define QPB      512      // quad-pairs per bin block -> 4096 records
#define GC_STRIDE 32      // gcnt padding: 128 B per counter

__device__ __forceinline__ unsigned pack_rec(int atom, float e) {
    unsigned h = (unsigned)__half_as_ushort(__float2half(e));
    return (h << 16) | ((unsigned)atom & (SL_SZ - 1));   // low 14 bits keep class
}

// K1: fused energy + 256-way binning via LDS rtn-atomic staging (r7-proven,
// measured 102 us at 2 blocks/CU). Now: 30 KB LDS -> 5 blocks/CU so the
// LDS-atomic pipe (the 82 us floor) stays saturated while loads/dump overlap.
__global__ __launch_bounds__(256, 5)
void bin_kernel(const int4* __restrict__ pairs4, const float4* __restrict__ dist4,
                unsigned* __restrict__ grec, unsigned* __restrict__ gcnt,
                int npair4, int cap) {
    __shared__ unsigned staged[NB * BCAP];   // 28 KB
    __shared__ unsigned cnt[NB];             // 1 KB
    __shared__ unsigned gbase[NB];           // 1 KB
    const int tid = threadIdx.x;
    cnt[tid] = 0;   // blockDim == NB == 256
    __syncthreads();

#define STAGE(atom, ev)                                                        \
    do {                                                                       \
        int _a = (atom);                                                       \
        int _b = (unsigned)_a >> 10;                                           \
        unsigned _r = pack_rec(_a, (ev));                                      \
        unsigned _pos = atomicAdd(&cnt[_b], 1u);                               \
        if (_pos < BCAP) {                                                     \
            staged[_b * BCAP + _pos] = _r;                                     \
        } else {   /* ~3-sigma tail: direct global append */                   \
            unsigned _gi = atomicAdd(&gcnt[_b * GC_STRIDE], 1u);               \
            if (_gi < (unsigned)cap) grec[(size_t)_b * cap + _gi] = _r;        \
        }                                                                      \
    } while (0)

    for (int k = 0; k < 2; ++k) {
        int q = blockIdx.x * QPB + (k << 8) + tid;
        if (q < npair4) {
            int4 pA = pairs4[2 * q];
            int4 pB = pairs4[2 * q + 1];
            float4 d0 = dist4[3 * q], d1 = dist4[3 * q + 1], d2 = dist4[3 * q + 2];
            float e0 = half_lj(fmaf(d0.x, d0.x, fmaf(d0.y, d0.y, d0.z * d0.z)));
            float e1 = half_lj(fmaf(d0.w, d0.w, fmaf(d1.x, d1.x, d1.y * d1.y)));
            float e2 = half_lj(fmaf(d1.z, d1.z, fmaf(d1.w, d1.w, d2.x * d2.x)));
            float e3 = half_lj(fmaf(d2.y, d2.y, fmaf(d2.z, d2.z, d2.w * d2.w)));
            STAGE(pA.x, e0); STAGE(pA.y, e0);
            STAGE(pA.z, e1); STAGE(pA.w, e1);
            STAGE(pB.x, e2); STAGE(pB.y, e2);
            STAGE(pB.z, e3); STAGE(pB.w, e3);
        }
    }
#undef STAGE
    __syncthreads();

    // one padded-line reservation atomic per (block,bucket)
    {
        unsigned c = cnt[tid] < BCAP ? cnt[tid] : BCAP;
        gbase[tid] = atomicAdd(&gcnt[tid * GC_STRIDE], c);
    }
    __syncthreads();

    // slot-parallel dump: NB*BCAP = 7168 slots, 28 iterations
    for (int idx = tid; idx < NB * BCAP; idx += 256) {
        int b = idx / BCAP;
        int i = idx - b * BCAP;
        unsigned c = cnt[b] < BCAP ? cnt[b] : BCAP;
        if ((unsigned)i < c) {
            unsigned pos = gbase[b] + (unsigned)i;
            if (pos < (unsigned)cap)
                grec[(size_t)b * cap + pos] = staged[idx];
        }
    }
}

// K1 tail: leftover pairs (npairs % 4), direct global append.
__global__ void bin_tail_kernel(const int* __restrict__ pairs,
                                const float* __restrict__ dist,
                                unsigned* __restrict__ grec,
                                unsigned* __restrict__ gcnt,
                                int start, int npairs, int cap) {
    int i = start + blockIdx.x * 64 + threadIdx.x;
    if (i >= npairs) return;
    float dx = dist[3 * i], dy = dist[3 * i + 1], dz = dist[3 * i + 2];
    float h = half_lj(fmaf(dx, dx, fmaf(dy, dy, dz * dz)));
    int a0 = pairs[2 * i], a1 = pairs[2 * i + 1];
    int b0 = (unsigned)a0 >> 10, b1 = (unsigned)a1 >> 10;
    unsigned g0 = atomicAdd(&gcnt[b0 * GC_STRIDE], 1u);
    if (g0 < (unsigned)cap) grec[(size_t)b0 * cap + g0] = pack_rec(a0, h);
    unsigned g1 = atomicAdd(&gcnt[b1 * GC_STRIDE], 1u);
    if (g1 < (unsigned)cap) grec[(size_t)b1 * cap + g1] = pack_rec(a1, h);
}

// K2: r7-validated tag-claim accum (ZERO atomics, measured ~17 us).
// Block (s,c), wave w consumes chunk c of bucket (s<<4)|w; wave-exclusive
// 1024-atom region; intra-wave same-address races via tag-claim retry.
__global__ __launch_bounds__(1024)
void accum_tag_kernel(const unsigned* __restrict__ grec,
                      const unsigned* __restrict__ gcnt,
                      float* __restrict__ rep,
                      int cap, int CH, int n_pad) {
    __shared__ float acc[SL_SZ];            // 64 KB
    __shared__ unsigned char tagm[SL_SZ];   // 16 KB (never needs init)
    volatile unsigned char* vtag = tagm;
    const int s = blockIdx.x / CH;
    const int c = blockIdx.x % CH;
    const int tid = threadIdx.x;
    const int wave = tid >> 6;
    const int lane = tid & 63;

    float4* acc4 = (float4*)acc;
    for (int i = tid; i < SL_SZ / 4; i += 1024)
        acc4[i] = make_float4(0.f, 0.f, 0.f, 0.f);
    __syncthreads();

    const int g = (s << 4) | wave;
    int M = (int)gcnt[g * GC_STRIDE];
    if (M > cap) M = cap;
    const unsigned* base = grec + (size_t)g * cap;
    const int beg = (int)((long long)c * M / CH);
    const int end = (int)((long long)(c + 1) * M / CH);

    for (int jj = beg; jj < end; jj += 64) {
        int j = jj + lane;
        bool valid = j < end;
        unsigned rec = valid ? base[j] : 0u;
        int a = rec & (SL_SZ - 1);
        float v = __half2float(__ushort_as_half((unsigned short)(rec >> 16)));
        bool active = valid;
        while (__any(active)) {
            if (active) vtag[a] = (unsigned char)lane;
            if (active && vtag[a] == (unsigned char)lane) {
                acc[a] += v;
                active = false;
            }
        }
    }
    __syncthreads();

    float4* rep4 = (float4*)(rep + (size_t)c * n_pad + (size_t)s * SL_SZ);
    for (int i = tid; i < SL_SZ / 4; i += 1024)
        rep4[i] = acc4[i];
}

// K3: out = sum over CH replicas.
__global__ void reduce_reps_kernel(const float* __restrict__ rep,
                                   float* __restrict__ out,
                                   int n_atoms, int n_pad, int B) {
    int i4 = blockIdx.x * blockDim.x + threadIdx.x;
    int n4 = n_atoms / 4;
    if (i4 < n4) {
        float4 sum = make_float4(0.f, 0.f, 0.f, 0.f);
        for (int b = 0; b < B; ++b) {
            float4 v = *(const float4*)(rep + (size_t)b * n_pad + 4 * (size_t)i4);
            sum.x += v.x; sum.y += v.y; sum.z += v.z; sum.w += v.w;
        }
        ((float4*)out)[i4] = sum;
    }
    if (i4 == 0) {
        for (int i = n4 * 4; i < n_atoms; ++i) {
            float sum = 0.f;
            for (int b = 0; b < B; ++b) sum += rep[(size_t)b * n_pad + i];
            out[i] = sum;
        }
    }
}

// ---------- Path B fallback: slice-scan (measured 125 us) ----------
#define PB_SHIFT 15
#define PB_SZ 32768

__global__ void compute_e8_kernel(const float4* __restrict__ dist4,
                                  uint4* __restrict__ e8, int npair8) {
    int t = blockIdx.x * blockDim.x + threadIdx.x;
    if (t >= npair8) return;
    float4 v0 = dist4[6 * t + 0], v1 = dist4[6 * t + 1], v2 = dist4[6 * t + 2];
    float4 v3 = dist4[6 * t + 3], v4 = dist4[6 * t + 4], v5 = dist4[6 * t + 5];
    float h0 = half_lj(fmaf(v0.x, v0.x, fmaf(v0.y, v0.y, v0.z * v0.z)));
    float h1 = half_lj(fmaf(v0.w, v0.w, fmaf(v1.x, v1.x, v1.y * v1.y)));
    float h2 = half_lj(fmaf(v1.z, v1.z, fmaf(v1.w, v1.w, v2.x * v2.x)));
    float h3 = half_lj(fmaf(v2.y, v2.y, fmaf(v2.z, v2.z, v2.w * v2.w)));
    float h4 = half_lj(fmaf(v3.x, v3.x, fmaf(v3.y, v3.y, v3.z * v3.z)));
    float h5 = half_lj(fmaf(v3.w, v3.w, fmaf(v4.x, v4.x, v4.y * v4.y)));
    float h6 = half_lj(fmaf(v4.z, v4.z, fmaf(v4.w, v4.w, v5.x * v5.x)));
    float h7 = half_lj(fmaf(v5.y, v5.y, fmaf(v5.z, v5.z, v5.w * v5.w)));
    union { __half2 h; unsigned u; } c01, c23, c45, c67;
    c01.h = __floats2half2_rn(h0, h1);
    c23.h = __floats2half2_rn(h2, h3);
    c45.h = __floats2half2_rn(h4, h5);
    c67.h = __floats2half2_rn(h6, h7);
    uint4 o; o.x = c01.u; o.y = c23.u; o.z = c45.u; o.w = c67.u;
    e8[t] = o;
}

__global__ void compute_e_tail_kernel(const float* __restrict__ dist,
                                      __half* __restrict__ eh,
                                      int start, int npairs) {
    int i = start + blockIdx.x * blockDim.x + threadIdx.x;
    if (i >= npairs) return;
    float dx = dist[3 * i], dy = dist[3 * i + 1], dz = dist[3 * i + 2];
    eh[i] = __float2half(half_lj(fmaf(dx, dx, fmaf(dy, dy, dz * dz))));
}

__global__ __launch_bounds__(1024, 1)
void accum_slice_kernel(const int4* __restrict__ pairs4,
                        const uint2* __restrict__ eh2,
                        const int* __restrict__ pairs,
                        const __half* __restrict__ eh,
                        float* __restrict__ rep,
                        int npair4, int npairs, int nslices, int B, int n_pad) {
    __shared__ float lds[PB_SZ];
    int gid = blockIdx.x;
    int s = gid % nslices;
    int b = gid / nslices;
    const int tid = threadIdx.x;
    const int base = s << PB_SHIFT;

    float4* lds4 = (float4*)lds;
    for (int i = tid; i < PB_SZ / 4; i += 1024)
        lds4[i] = make_float4(0.f, 0.f, 0.f, 0.f);
    __syncthreads();

    const int qb = (int)((long long)b * npair4 / B);
    const int qe = (int)((long long)(b + 1) * npair4 / B);

#define CHK(atom, val)                                           \
    do {                                                         \
        int _t = (atom) - base;                                  \
        if ((unsigned)_t < PB_SZ) atomicAdd(&lds[_t], (val));    \
    } while (0)

    for (int q = qb + tid; q < qe; q += 1024) {
        int4 pA = pairs4[2 * q];
        int4 pB = pairs4[2 * q + 1];
        uint2 ue = eh2[q];
        union { unsigned u; __half2 h; } a_, b_;
        a_.u = ue.x; b_.u = ue.y;
        float2 e01 = __half22float2(a_.h);
        float2 e23 = __half22float2(b_.h);
        CHK(pA.x, e01.x); CHK(pA.y, e01.x);
        CHK(pA.z, e01.y); CHK(pA.w, e01.y);
        CHK(pB.x, e23.x); CHK(pB.y, e23.x);
        CHK(pB.z, e23.y); CHK(pB.w, e23.y);
    }
    if (b == 0) {
        for (int i = npair4 * 4 + tid; i < npairs; i += 1024) {
            int a0 = pairs[2 * i], a1 = pairs[2 * i + 1];
            float h = __half2float(eh[i]);
            CHK(a0, h);
            CHK(a1, h);
        }
    }
#undef CHK
    __syncthreads();

    float4* rep4 = (float4*)(rep + (size_t)b * n_pad + (size_t)s * PB_SZ);
    for (int i = tid; i < PB_SZ / 4; i += 1024)
        rep4[i] = lds4[i];
}

// ---------- Path C fallback: direct agent atomics (measured 803 us) ----------
__global__ void lj_vec4_agent_kernel(const int4* __restrict__ pairs4,
                                     const float4* __restrict__ dist4,
                                     float* __restrict__ out, int npair4) {
    int t = blockIdx.x * blockDim.x + threadIdx.x;
    if (t >= npair4) return;
    int4 p01 = pairs4[2 * t];
    int4 p23 = pairs4[2 * t + 1];
    float4 d0 = dist4[3 * t];
    float4 d1 = dist4[3 * t + 1];
    float4 d2 = dist4[3 * t + 2];
    float h0 = half_lj(fmaf(d0.x, d0.x, fmaf(d0.y, d0.y, d0.z * d0.z)));
    float h1 = half_lj(fmaf(d0.w, d0.w, fmaf(d1.x, d1.x, d1.y * d1.y)));
    float h2 = half_lj(fmaf(d1.z, d1.z, fmaf(d1.w, d1.w, d2.x * d2.x)));
    float h3 = half_lj(fmaf(d2.y, d2.y, fmaf(d2.z, d2.z, d2.w * d2.w)));
    unsafeAtomicAdd(&out[p01.x], h0);
    unsafeAtomicAdd(&out[p01.y], h0);
    unsafeAtomicAdd(&out[p01.z], h1);
    unsafeAtomicAdd(&out[p01.w], h1);
    unsafeAtomicAdd(&out[p23.x], h2);
    unsafeAtomicAdd(&out[p23.y], h2);
    unsafeAtomicAdd(&out[p23.z], h3);
    unsafeAtomicAdd(&out[p23.w], h3);
}

__global__ void lj_tail_agent_kernel(const int* __restrict__ pairs,
                                     const float* __restrict__ dist,
                                     float* __restrict__ out,
                                     int start, int npairs) {
    int i = start + blockIdx.x * blockDim.x + threadIdx.x;
    if (i >= npairs) return;
    float dx = dist[3 * i], dy = dist[3 * i + 1], dz = dist[3 * i + 2];
    float h = half_lj(fmaf(dx, dx, fmaf(dy, dy, dz * dz)));
    unsafeAtomicAdd(&out[pairs[2 * i]], h);
    unsafeAtomicAdd(&out[pairs[2 * i + 1]], h);
}

extern "C" void kernel_launch(void* const* d_in, const int* in_sizes, int n_in,
                              void* d_out, int out_size, void* d_ws, size_t ws_size,
                              hipStream_t stream) {
    const int* pairs = (const int*)d_in[0];      // [P, 2] int32
    const float* dist = (const float*)d_in[1];   // [P, 3] float32
    float* out = (float*)d_out;                  // [n_atoms] float32

    const int n_atoms = out_size;
    const int npairs = in_sizes[0] / 2;
    const int npair4 = npairs / 4;

    // ---- Path A: occupancy-tuned r7 pipeline ----
    if (n_atoms <= NB * 1024 && npairs > 0) {
        const int nslices = (n_atoms + SL_SZ - 1) >> SL_SHIFT;
        const int n_pad = nslices << SL_SHIFT;
        // per-bucket mean 2P/256 (=65536 here), sigma ~256; +2048 = 8 sigma
        int cap = (int)(2LL * npairs / NB + 2048);
        size_t cnt_bytes = (size_t)NB * GC_STRIDE * 4;   // 32 KB padded counters
        size_t rec_bytes = (size_t)NB * (size_t)cap * 4;
        int CH = 32;
        while (CH > 4 &&
               cnt_bytes + rec_bytes + (size_t)CH * (size_t)n_pad * 4 > ws_size)
            CH >>= 1;
        size_t need = cnt_bytes + rec_bytes + (size_t)CH * (size_t)n_pad * 4;
        if (need <= ws_size) {
            unsigned* gcnt = (unsigned*)d_ws;
            unsigned* grec = (unsigned*)((char*)d_ws + cnt_bytes);
            float* rep = (float*)((char*)d_ws + cnt_bytes + rec_bytes);

            hipMemsetAsync(gcnt, 0, cnt_bytes, stream);

            int nb = (npair4 + QPB - 1) / QPB;
            if (nb > 0)
                bin_kernel<<<nb, 256, 0, stream>>>(
                    (const int4*)pairs, (const float4*)dist, grec, gcnt,
                    npair4, cap);
            if (npair4 * 4 < npairs)
                bin_tail_kernel<<<1, 64, 0, stream>>>(pairs, dist, grec, gcnt,
                                                      npair4 * 4, npairs, cap);

            accum_tag_kernel<<<nslices * CH, 1024, 0, stream>>>(
                grec, gcnt, rep, cap, CH, n_pad);

            int n4 = n_atoms / 4;
            int grid = (n4 + 255) / 256;
            if (grid == 0) grid = 1;
            reduce_reps_kernel<<<grid, 256, 0, stream>>>(rep, out, n_atoms,
                                                         n_pad, CH);
            return;
        }
    }

    // ---- Path B: slice-scan ----
    {
        const int nsl = (n_atoms + PB_SZ - 1) >> PB_SHIFT;
        const int n_pad = nsl << PB_SHIFT;
        const size_t e_elems = (size_t)((npairs + 7) / 8) * 8;
        const size_t e_bytes = e_elems * sizeof(__half);
        int B = 32;
        while (B > 8 && e_bytes + (size_t)B * n_pad * sizeof(float) > ws_size)
            B >>= 1;
        if (e_bytes + (size_t)B * n_pad * sizeof(float) <= ws_size) {
            __half* eh = (__half*)d_ws;
            float* rep = (float*)((char*)d_ws + e_bytes);
            int npair8 = npairs / 8;
            if (npair8 > 0)
                compute_e8_kernel<<<(npair8 + 255) / 256, 256, 0, stream>>>(
                    (const float4*)dist, (uint4*)eh, npair8);
            if (npair8 * 8 < npairs)
                compute_e_tail_kernel<<<1, 64, 0, stream>>>(dist, eh,
                                                            npair8 * 8, npairs);
            accum_slice_kernel<<<nsl * B, 1024, 0, stream>>>(
                (const int4*)pairs, (const uint2*)eh, pairs, eh, rep,
                npair4, npairs, nsl, B, n_pad);
            int n4 = n_atoms / 4;
            int grid = (n4 + 255) / 256;
            if (grid == 0) grid = 1;
            reduce_reps_kernel<<<grid, 256, 0, stream>>>(rep, out, n_atoms,
                                                         n_pad, B);
            return;
        }
    }

    // ---- Path C: direct atomics ----
    hipMemsetAsync(d_out, 0, (size_t)out_size * sizeof(float), stream);
    if (npair4 > 0)
        lj_vec4_agent_kernel<<<(npair4 + 255) / 256, 256, 0, stream>>>(
            (const int4*)pairs, (const float4*)dist, out, npair4);
    if (npair4 * 4 < npairs)
        lj_tail_agent_kernel<<<1, 64, 0, stream>>>(pairs, dist, out,
                                                   npair4 * 4, npairs);
}